// Round 2
// baseline (469.712 us; speedup 1.0000x reference)
//
#include <hip/hip_runtime.h>
#include <math.h>

#define IH 2048
#define IW 2048
#define NBATCH 8
#define TW 64            // tile width  (output)
#define TH 32            // tile height (output)
#define HALO 3
#define SR (TH + 2*HALO) // 38 staged rows
#define SROW 72          // padded row stride (floats) for s_img
#define ACT_TH 0.1f
#define IMP_TH 0.1f

// 1D Gaussian taps, sigma = 7/6, normalized.
#define G0 0.0125602013f
#define G1 0.0788279697f
#define G2 0.2372960895f
#define G3 0.3426314790f

// ---------------- Kernel 1: per-batch max --------------------------------
__global__ __launch_bounds__(256) void batch_max_kernel(
    const float* __restrict__ x, unsigned int* __restrict__ maxbits)
{
    const int b = blockIdx.y;
    const float4* p = (const float4*)(x + (size_t)b * (size_t)(IH * IW));
    const int n4 = IH * IW / 4;
    float m = 0.0f;
    for (int i = blockIdx.x * blockDim.x + threadIdx.x; i < n4;
         i += gridDim.x * blockDim.x) {
        float4 v = p[i];
        m = fmaxf(m, fmaxf(fmaxf(v.x, v.y), fmaxf(v.z, v.w)));
    }
#pragma unroll
    for (int s = 1; s < 64; s <<= 1) m = fmaxf(m, __shfl_xor(m, s));
    __shared__ float sm[4];
    const int lane = threadIdx.x & 63, wv = threadIdx.x >> 6;
    if (lane == 0) sm[wv] = m;
    __syncthreads();
    if (threadIdx.x == 0) {
        m = fmaxf(fmaxf(sm[0], sm[1]), fmaxf(sm[2], sm[3]));
        // x >= 0, so uint-bit compare == float compare
        atomicMax(&maxbits[b], __float_as_uint(m));
    }
}

// ---------------- Kernel 2: fused normalize + block stats ----------------
// 64x32 output tile per WG. LDS ~30.5KB -> 5 WG/CU (20 waves, 62% occ).
__global__ __launch_bounds__(256, 5) void piqe_main_kernel(
    const float* __restrict__ x, const unsigned int* __restrict__ maxbits,
    float* __restrict__ contrib_sum, unsigned int* __restrict__ nhsa)
{
    __shared__ float s_img[SR * SROW];   // 38x72 img; later MSCN n in-place
    __shared__ float s_mu[SR * TW];      // horizontal conv of img   (38x64)
    __shared__ float s_mu2[SR * TW];     // horizontal conv of img^2 (38x64)
    __shared__ float s_c;
    __shared__ unsigned int s_a;

    const int tid = threadIdx.x;
    const int b = blockIdx.z;
    const int ox = blockIdx.x * TW;
    const int oy = blockIdx.y * TH;
    const float* img0 = x + (size_t)b * (size_t)(IH * IW);
    const float scale = 255.0f / __uint_as_float(maxbits[b]);

    if (tid == 0) { s_c = 0.0f; s_a = 0u; }

    // ---- Phase A: load 38x70 halo tile (edge-clamped), img = rint(x*scale)
    {
        const int c = tid & 63;
        const int r0 = tid >> 6;
        int gx = ox + c - HALO; gx = max(0, min(IW - 1, gx));
        for (int r = r0; r < SR; r += 4) {
            int gy = oy + r - HALO; gy = max(0, min(IH - 1, gy));
            s_img[r * SROW + c] = rintf(img0[(size_t)gy * IW + gx] * scale);
        }
        if (c < 6) {                       // cols 64..69
            int gx2 = min(IW - 1, ox + c + (TW - HALO));
            for (int r = r0; r < SR; r += 4) {
                int gy = oy + r - HALO; gy = max(0, min(IH - 1, gy));
                s_img[r * SROW + c + 64] =
                    rintf(img0[(size_t)gy * IW + gx2] * scale);
            }
        }
    }
    __syncthreads();

    // ---- Phase B: horizontal 7-tap (img, img^2) -> s_mu/s_mu2 (38x64)
    // thread = (row = tid>>3, 8-col chunk = (tid&7)*8); vector LDS loads.
    {
        const int cc = (tid & 7) << 3;
        const float gk[7] = {G0, G1, G2, G3, G2, G1, G0};
        for (int rr = tid >> 3; rr < SR; rr += 32) {
            const float* p = &s_img[rr * SROW + cc];   // 16B-aligned
            float v[14];
            *(float4*)(v)     = *(const float4*)(p);
            *(float4*)(v + 4) = *(const float4*)(p + 4);
            *(float4*)(v + 8) = *(const float4*)(p + 8);
            *(float2*)(v +12) = *(const float2*)(p + 12);
            float q[14];
#pragma unroll
            for (int i = 0; i < 14; ++i) q[i] = v[i] * v[i];
            float om[8], om2[8];
#pragma unroll
            for (int j = 0; j < 8; ++j) {
                float m = 0.0f, m2 = 0.0f;
#pragma unroll
                for (int k = 0; k < 7; ++k) {
                    m  = fmaf(gk[k], v[j + k], m);
                    m2 = fmaf(gk[k], q[j + k], m2);
                }
                om[j] = m; om2[j] = m2;
            }
            float* dm = &s_mu[rr * TW + cc];
            *(float4*)(dm)     = *(const float4*)(om);
            *(float4*)(dm + 4) = *(const float4*)(om + 4);
            float* d2 = &s_mu2[rr * TW + cc];
            *(float4*)(d2)     = *(const float4*)(om2);
            *(float4*)(d2 + 4) = *(const float4*)(om2 + 4);
        }
    }
    __syncthreads();

    // ---- Phase C: vertical 7-tap, n = (img-mu)/(std+1) in-place in s_img.
    // thread = (col = tid&63, vertical run of 8 rows). Reads only own pixels.
    {
        const int c = tid & 63;
        const int r0 = (tid >> 6) * 8;
        const float gk[7] = {G0, G1, G2, G3, G2, G1, G0};
        float mv[14], mv2[14];
#pragma unroll
        for (int i = 0; i < 14; ++i) {
            mv[i]  = s_mu [(r0 + i) * TW + c];
            mv2[i] = s_mu2[(r0 + i) * TW + c];
        }
#pragma unroll
        for (int i = 0; i < 8; ++i) {
            float m = 0.0f, m2 = 0.0f;
#pragma unroll
            for (int k = 0; k < 7; ++k) {
                m  = fmaf(gk[k], mv[i + k], m);
                m2 = fmaf(gk[k], mv2[i + k], m2);
            }
            float sd = __builtin_amdgcn_sqrtf(fabsf(m2 - m * m));
            int ii = (r0 + i + HALO) * SROW + (c + HALO);
            float pix = s_img[ii];
            s_img[ii] = (pix - m) * __builtin_amdgcn_rcpf(sd + 1.0f);
        }
    }
    __syncthreads();

    // ---- Phase D: per-16x16-block stats. 8 blocks; 32-lane team per block;
    // lane = (row = t&15, col half = t>>4, 8 cols each).
    {
        const int t = tid & 31;
        const int team = tid >> 5;             // 0..7
        const int bi = team >> 2, bj = team & 3;
        const int row = t & 15, half = t >> 4;
        const float* np0 = &s_img[(HALO + bi * 16) * SROW + (HALO + bj * 16)];
        const float* pr = np0 + row * SROW + half * 8;
        float rv[8];
#pragma unroll
        for (int k = 0; k < 8; ++k) rv[k] = pr[k];
        float s1 = 0.0f, s2 = 0.0f;
#pragma unroll
        for (int k = 0; k < 8; ++k) { s1 += rv[k]; s2 += rv[k] * rv[k]; }
        float ce = half ? rv[0] : rv[7];       // center cols {7,8}
        float c1 = ce, c2 = ce * ce;
        float ex = half ? rv[1] : rv[7];       // sur excludes cols {7,9}
        float u1 = s1 - ex, u2 = s2 - ex * ex;

        // Edge 11-window seg-std minima: lanes 0..3 of each team, one edge each
        float minstd = __builtin_inff();
        if (t < 4) {
            int offs, stp;
            if (t == 0)      { offs = 0;         stp = 1; }     // top
            else if (t == 1) { offs = 15 * SROW; stp = 1; }     // bottom
            else if (t == 2) { offs = 0;         stp = SROW; }  // left
            else             { offs = 15;        stp = SROW; }  // right
            float e[16];
#pragma unroll
            for (int k = 0; k < 16; ++k) e[k] = np0[offs + k * stp];
            float w1 = 0.0f, w2 = 0.0f;
#pragma unroll
            for (int k = 0; k < 6; ++k) { w1 += e[k]; w2 += e[k] * e[k]; }
#pragma unroll
            for (int i = 0; i < 11; ++i) {
                float var = (w2 - w1 * w1 * (1.0f / 6.0f)) * (1.0f / 5.0f);
                minstd = fminf(minstd,
                               __builtin_amdgcn_sqrtf(fmaxf(var, 0.0f)));
                if (i < 10) {
                    w1 += e[i + 6] - e[i];
                    w2 += e[i + 6] * e[i + 6] - e[i] * e[i];
                }
            }
        }

        // Butterfly reduction within each 32-lane team
#pragma unroll
        for (int m = 1; m < 32; m <<= 1) {
            s1 += __shfl_xor(s1, m);
            s2 += __shfl_xor(s2, m);
            c1 += __shfl_xor(c1, m);
            c2 += __shfl_xor(c2, m);
            u1 += __shfl_xor(u1, m);
            u2 += __shfl_xor(u2, m);
            minstd = fminf(minstd, __shfl_xor(minstd, m));
        }

        if (t == 0) {
            float bv = fmaxf((s2 - s1 * s1 * (1.0f / 256.0f)) * (1.0f / 255.0f), 0.0f);
            bool active = bv > ACT_TH;
            float cstd = __builtin_amdgcn_sqrtf(
                fmaxf((c2 - c1 * c1 * (1.0f / 32.0f)) * (1.0f / 31.0f), 0.0f));
            float sstd = __builtin_amdgcn_sqrtf(
                fmaxf((u2 - u1 * u1 * (1.0f / 224.0f)) * (1.0f / 223.0f), 0.0f));
            float csd = cstd / sstd;            // 0/0 -> NaN (matches ref)
            if (csd != csd) csd = 0.0f;
            float sigma = __builtin_amdgcn_sqrtf(bv);
            float beta = fabsf(sigma - csd) / fmaxf(sigma, csd);
            bool wnc = sigma > 2.0f * beta;     // NaN beta -> false (matches)
            bool impaired = minstd < IMP_TH;
            if (active) {
                float contrib = (impaired ? (1.0f - bv) : 0.0f) + (wnc ? bv : 0.0f);
                atomicAdd(&s_c, contrib);
                atomicAdd(&s_a, 1u);
            }
        }
    }
    __syncthreads();
    if (tid == 0) {
        atomicAdd(&contrib_sum[b], s_c);
        atomicAdd(&nhsa[b], s_a);
    }
}

// ---------------- Kernel 3: final score ----------------------------------
__global__ void piqe_finish_kernel(const float* __restrict__ contrib_sum,
                                   const unsigned int* __restrict__ nhsa,
                                   float* __restrict__ out)
{
    int b = threadIdx.x;
    if (b < NBATCH)
        out[b] = (contrib_sum[b] + 1.0f) / (1.0f + (float)nhsa[b]) * 100.0f;
}

extern "C" void kernel_launch(void* const* d_in, const int* in_sizes, int n_in,
                              void* d_out, int out_size, void* d_ws, size_t ws_size,
                              hipStream_t stream)
{
    const float* x = (const float*)d_in[0];
    float* out = (float*)d_out;

    unsigned int* maxbits = (unsigned int*)d_ws;                 // 8 u32
    float* contrib = (float*)((char*)d_ws + 32);                 // 8 f32
    unsigned int* nhsa = (unsigned int*)((char*)d_ws + 64);      // 8 u32

    hipMemsetAsync(d_ws, 0, 96, stream);
    batch_max_kernel<<<dim3(256, NBATCH), 256, 0, stream>>>(x, maxbits);
    piqe_main_kernel<<<dim3(IW / TW, IH / TH, NBATCH), 256, 0, stream>>>(
        x, maxbits, contrib, nhsa);
    piqe_finish_kernel<<<1, 64, 0, stream>>>(contrib, nhsa, out);
}